// Round 1
// baseline (940.393 us; speedup 1.0000x reference)
//
#include <hip/hip_runtime.h>
#include <hip/hip_bf16.h>
#include <math.h>

// Problem constants
#define LL 13
#define BB 16
#define SS 512
#define HH 768
#define HDD 32
#define NN (BB*SS)      // 8192 tokens
#define NT (LL*NN)      // 106496 GEMM rows

// ---------------------------------------------------------------------------
// K1: input projection GEMM (fp32, VALU).
// A = hidden_states viewed as [NT, 768] row-major (row r = t*N + n).
// C = A @ [Wi_f | Wi_b] + [b_f[0] | b_b[0]]  -> xpf[NT,96], xpb[NT,96]
// Tile: 64 rows x 192 cols (all cols), BK=16. 256 threads, 48 acc/thread.
// ---------------------------------------------------------------------------
__global__ __launch_bounds__(256) void k_proj(
    const float* __restrict__ A, const float* __restrict__ Wf,
    const float* __restrict__ Wb, const float* __restrict__ bfv,
    const float* __restrict__ bbv, float* __restrict__ xpf,
    float* __restrict__ xpb)
{
    __shared__ float Al[16 * 68];    // [k][row], stride 68 (pad: bank-spread)
    __shared__ float Wl[16 * 192];   // [k][col]

    const int t  = threadIdx.x;
    const int r0 = blockIdx.x * 64;
    const int tr = t >> 4;           // 0..15 -> rows 4*tr..4*tr+3
    const int tc = t & 15;           // 0..15 -> cols 12*tc..12*tc+11

    float acc[4][12];
    #pragma unroll
    for (int i = 0; i < 4; ++i)
        #pragma unroll
        for (int j = 0; j < 12; ++j) acc[i][j] = 0.f;

    const int lrow = t >> 2;         // 0..63 (A staging row)
    const int lc4  = t & 3;          // 0..3  (A staging k-chunk)

    for (int k0 = 0; k0 < HH; k0 += 16) {
        // stage A tile (transposed into [k][row])
        float4 av = *(const float4*)(A + (size_t)(r0 + lrow) * HH + k0 + lc4 * 4);
        Al[(lc4 * 4 + 0) * 68 + lrow] = av.x;
        Al[(lc4 * 4 + 1) * 68 + lrow] = av.y;
        Al[(lc4 * 4 + 2) * 68 + lrow] = av.z;
        Al[(lc4 * 4 + 3) * 68 + lrow] = av.w;
        // stage W tile: 16 rows x 192 cols = 768 float4s, 3 per thread
        #pragma unroll
        for (int i = 0; i < 3; ++i) {
            int f = t + i * 256;
            int row = f / 48, c4 = f - row * 48;
            const float* src = (c4 < 24)
                ? (Wf + (size_t)(k0 + row) * 96 + c4 * 4)
                : (Wb + (size_t)(k0 + row) * 96 + (c4 - 24) * 4);
            *(float4*)(&Wl[row * 192 + c4 * 4]) = *(const float4*)src;
        }
        __syncthreads();
        #pragma unroll
        for (int k = 0; k < 16; ++k) {
            float4 a4 = *(const float4*)(&Al[k * 68 + tr * 4]);
            float a[4] = {a4.x, a4.y, a4.z, a4.w};
            float w[12];
            *(float4*)(&w[0]) = *(const float4*)(&Wl[k * 192 + tc * 12 + 0]);
            *(float4*)(&w[4]) = *(const float4*)(&Wl[k * 192 + tc * 12 + 4]);
            *(float4*)(&w[8]) = *(const float4*)(&Wl[k * 192 + tc * 12 + 8]);
            #pragma unroll
            for (int i = 0; i < 4; ++i)
                #pragma unroll
                for (int j = 0; j < 12; ++j)
                    acc[i][j] = fmaf(a[i], w[j], acc[i][j]);
        }
        __syncthreads();
    }

    // epilogue: +bias, vectorized stores (thread's 12 cols are contiguous and
    // never cross the f/b boundary at col 96 since 96 = 8*12)
    const int col = tc * 12;
    float bias[12];
    if (tc < 8) {
        #pragma unroll
        for (int j = 0; j < 12; ++j) bias[j] = bfv[col + j];
        #pragma unroll
        for (int i = 0; i < 4; ++i) {
            size_t row = (size_t)(r0 + tr * 4 + i);
            float o[12];
            #pragma unroll
            for (int j = 0; j < 12; ++j) o[j] = acc[i][j] + bias[j];
            *(float4*)(xpf + row * 96 + col + 0) = *(float4*)(&o[0]);
            *(float4*)(xpf + row * 96 + col + 4) = *(float4*)(&o[4]);
            *(float4*)(xpf + row * 96 + col + 8) = *(float4*)(&o[8]);
        }
    } else {
        const int colb = col - 96;
        #pragma unroll
        for (int j = 0; j < 12; ++j) bias[j] = bbv[colb + j];
        #pragma unroll
        for (int i = 0; i < 4; ++i) {
            size_t row = (size_t)(r0 + tr * 4 + i);
            float o[12];
            #pragma unroll
            for (int j = 0; j < 12; ++j) o[j] = acc[i][j] + bias[j];
            *(float4*)(xpb + row * 96 + colb + 0) = *(float4*)(&o[0]);
            *(float4*)(xpb + row * 96 + colb + 4) = *(float4*)(&o[4]);
            *(float4*)(xpb + row * 96 + colb + 8) = *(float4*)(&o[8]);
        }
    }
}

// ---------------------------------------------------------------------------
// K2: GRU scans (fw + bw), 8 lanes per sequence, each lane owns 4 hidden
// units (rec columns j, 32+j, 64+j). Uh staged in LDS; h replicated across
// the 8 lanes and redistributed each step via __shfl(width=8).
// Writes lc[n][32] = h_fw + h_bw.
// ---------------------------------------------------------------------------
__device__ __forceinline__ void gru_scan(
    const float* __restrict__ xp, const float* __restrict__ U,
    const float* __restrict__ br, int seq, int lane8, bool rev,
    float own[4])
{
    float h[32];
    #pragma unroll
    for (int m = 0; m < 32; ++m) h[m] = 0.f;
    float hown[4] = {0.f, 0.f, 0.f, 0.f};   // own units (avoids dynamic h[] index)

    #pragma unroll 1
    for (int step = 0; step < LL; ++step) {
        const int tt = rev ? (LL - 1 - step) : step;
        const float* xr = xp + ((size_t)tt * NN + seq) * 96;
        float4 xz4 = *(const float4*)(xr + 4 * lane8);
        float4 xr4 = *(const float4*)(xr + 32 + 4 * lane8);
        float4 xh4 = *(const float4*)(xr + 64 + 4 * lane8);

        float rz[4], rr[4], rh[4];
        #pragma unroll
        for (int u = 0; u < 4; ++u) {
            rz[u] = br[4 * lane8 + u];
            rr[u] = br[32 + 4 * lane8 + u];
            rh[u] = br[64 + 4 * lane8 + u];
        }
        #pragma unroll
        for (int m = 0; m < 32; ++m) {
            const float hm = h[m];
            float4 uz = *(const float4*)(U + m * 96 + 4 * lane8);
            float4 ur = *(const float4*)(U + m * 96 + 32 + 4 * lane8);
            float4 uh = *(const float4*)(U + m * 96 + 64 + 4 * lane8);
            rz[0] = fmaf(hm, uz.x, rz[0]); rz[1] = fmaf(hm, uz.y, rz[1]);
            rz[2] = fmaf(hm, uz.z, rz[2]); rz[3] = fmaf(hm, uz.w, rz[3]);
            rr[0] = fmaf(hm, ur.x, rr[0]); rr[1] = fmaf(hm, ur.y, rr[1]);
            rr[2] = fmaf(hm, ur.z, rr[2]); rr[3] = fmaf(hm, ur.w, rr[3]);
            rh[0] = fmaf(hm, uh.x, rh[0]); rh[1] = fmaf(hm, uh.y, rh[1]);
            rh[2] = fmaf(hm, uh.z, rh[2]); rh[3] = fmaf(hm, uh.w, rh[3]);
        }
        const float xz[4]  = {xz4.x, xz4.y, xz4.z, xz4.w};
        const float xrr[4] = {xr4.x, xr4.y, xr4.z, xr4.w};
        const float xh[4]  = {xh4.x, xh4.y, xh4.z, xh4.w};
        float hn[4];
        #pragma unroll
        for (int u = 0; u < 4; ++u) {
            float z  = 1.f / (1.f + __expf(-(xz[u] + rz[u])));
            float r  = 1.f / (1.f + __expf(-(xrr[u] + rr[u])));
            float hh = tanhf(xh[u] + r * rh[u]);
            hn[u] = z * hown[u] + (1.f - z) * hh;
        }
        #pragma unroll
        for (int u = 0; u < 4; ++u) hown[u] = hn[u];
        #pragma unroll
        for (int m = 0; m < 32; ++m)
            h[m] = __shfl(hn[m & 3], m >> 2, 8);
    }
    #pragma unroll
    for (int u = 0; u < 4; ++u) own[u] = hown[u];
}

__global__ __launch_bounds__(256) void k_gru(
    const float* __restrict__ xpf, const float* __restrict__ xpb,
    const float* __restrict__ Uhf, const float* __restrict__ Uhb,
    const float* __restrict__ bfv, const float* __restrict__ bbv,
    float* __restrict__ lc)
{
    __shared__ float Uf[32 * 96], Ub[32 * 96];
    __shared__ float brf[96], brb[96];
    const int t = threadIdx.x;
    for (int i = t; i < 32 * 96; i += 256) { Uf[i] = Uhf[i]; Ub[i] = Uhb[i]; }
    if (t < 96) { brf[t] = bfv[96 + t]; brb[t] = bbv[96 + t]; }
    __syncthreads();

    const int lane8 = t & 7;
    const int seq   = blockIdx.x * 32 + (t >> 3);

    float of[4], ob[4];
    gru_scan(xpf, Uf, brf, seq, lane8, false, of);
    gru_scan(xpb, Ub, brb, seq, lane8, true,  ob);

    float o[4];
    #pragma unroll
    for (int u = 0; u < 4; ++u) o[u] = of[u] + ob[u];
    *(float4*)(lc + (size_t)seq * 32 + 4 * lane8) = *(float4*)(&o[0]);
}

// ---------------------------------------------------------------------------
// K3: corrected = hs_last + tanh(lc @ W_lin + b_lin); partial sums over
// 32-token chunks. Grid (16, 16); thread owns cols {t, t+256, t+512};
// W_lin columns cached in registers (96 VGPR), lc rows staged in LDS.
// ---------------------------------------------------------------------------
__global__ __launch_bounds__(256) void k_corr(
    const float* __restrict__ hs_last, const float* __restrict__ lc,
    const float* __restrict__ Wlin, const float* __restrict__ blin,
    float* __restrict__ partial)
{
    __shared__ float lcl[32 * 32];
    const int t  = threadIdx.x;
    const int b  = blockIdx.x;   // 0..15
    const int sc = blockIdx.y;   // 0..15
    const int s0 = sc * 32;

    for (int i = t; i < 32 * 32; i += 256)
        lcl[i] = lc[((size_t)b * SS + s0) * 32 + i];
    __syncthreads();

    float Wc[32][3];
    #pragma unroll
    for (int j = 0; j < 32; ++j) {
        Wc[j][0] = Wlin[(size_t)j * HH + t];
        Wc[j][1] = Wlin[(size_t)j * HH + t + 256];
        Wc[j][2] = Wlin[(size_t)j * HH + t + 512];
    }
    const float bl0 = blin[t], bl1 = blin[t + 256], bl2 = blin[t + 512];

    float acc0 = 0.f, acc1 = 0.f, acc2 = 0.f;
    #pragma unroll 1
    for (int s = 0; s < 32; ++s) {
        float v0 = bl0, v1 = bl1, v2 = bl2;
        #pragma unroll
        for (int j = 0; j < 32; ++j) {
            const float l = lcl[s * 32 + j];
            v0 = fmaf(l, Wc[j][0], v0);
            v1 = fmaf(l, Wc[j][1], v1);
            v2 = fmaf(l, Wc[j][2], v2);
        }
        const float* hp = hs_last + ((size_t)b * SS + s0 + s) * HH;
        acc0 += hp[t]       + tanhf(v0);
        acc1 += hp[t + 256] + tanhf(v1);
        acc2 += hp[t + 512] + tanhf(v2);
    }
    float* pp = partial + ((size_t)b * 16 + sc) * HH;
    pp[t] = acc0; pp[t + 256] = acc1; pp[t + 512] = acc2;
}

// ---------------------------------------------------------------------------
// K4: final pooling + classifier + softmax (tiny). One block.
// ---------------------------------------------------------------------------
__global__ __launch_bounds__(256) void k_final(
    const float* __restrict__ partial, const float* __restrict__ Wcls,
    const float* __restrict__ bcls, float* __restrict__ out)
{
    __shared__ float pooled[16 * HH];
    __shared__ float logits[48];
    const int t = threadIdx.x;
    for (int i = t; i < 16 * HH; i += 256) {
        int b = i / HH, h = i - b * HH;
        float s = 0.f;
        #pragma unroll
        for (int c = 0; c < 16; ++c) s += partial[((size_t)b * 16 + c) * HH + h];
        pooled[i] = s * (1.f / (float)SS);
    }
    __syncthreads();
    if (t < 48) {
        int b = t / 3, c = t - (t / 3) * 3;
        float s = bcls[c];
        for (int h = 0; h < HH; ++h)
            s = fmaf(pooled[b * HH + h], Wcls[h * 3 + c], s);
        logits[t] = s;
    }
    __syncthreads();
    if (t < 16) {
        float l0 = logits[t * 3], l1 = logits[t * 3 + 1], l2 = logits[t * 3 + 2];
        float m = fmaxf(l0, fmaxf(l1, l2));
        float e0 = __expf(l0 - m), e1 = __expf(l1 - m), e2 = __expf(l2 - m);
        float inv = 1.f / (e0 + e1 + e2);
        out[t * 3 + 0] = e0 * inv;
        out[t * 3 + 1] = e1 * inv;
        out[t * 3 + 2] = e2 * inv;
    }
}

// ---------------------------------------------------------------------------
extern "C" void kernel_launch(void* const* d_in, const int* in_sizes, int n_in,
                              void* d_out, int out_size, void* d_ws, size_t ws_size,
                              hipStream_t stream)
{
    const float* hs    = (const float*)d_in[0];
    const float* Wi_f  = (const float*)d_in[1];
    const float* Uh_f  = (const float*)d_in[2];
    const float* b_f   = (const float*)d_in[3];
    const float* Wi_b  = (const float*)d_in[4];
    const float* Uh_b  = (const float*)d_in[5];
    const float* b_b   = (const float*)d_in[6];
    const float* W_lin = (const float*)d_in[7];
    const float* b_lin = (const float*)d_in[8];
    const float* W_cls = (const float*)d_in[9];
    const float* b_cls = (const float*)d_in[10];

    float* ws      = (float*)d_ws;
    float* xpf     = ws;                                // NT*96
    float* xpb     = xpf + (size_t)NT * 96;             // NT*96
    float* lc      = xpb + (size_t)NT * 96;             // N*32
    float* partial = lc + (size_t)NN * 32;              // 16*16*768
    float* out     = (float*)d_out;

    k_proj<<<NT / 64, 256, 0, stream>>>(hs, Wi_f, Wi_b, b_f, b_b, xpf, xpb);
    k_gru<<<NN / 32, 256, 0, stream>>>(xpf, xpb, Uh_f, Uh_b, b_f, b_b, lc);
    k_corr<<<dim3(16, 16), 256, 0, stream>>>(hs + (size_t)12 * NN * HH, lc,
                                             W_lin, b_lin, partial);
    k_final<<<1, 256, 0, stream>>>(partial, W_cls, b_cls, out);
}

// Round 5
// 590.823 us; speedup vs baseline: 1.5917x; 1.5917x over previous
//
#include <hip/hip_runtime.h>
#include <hip/hip_bf16.h>
#include <math.h>

// Problem constants
#define LL 13
#define BB 16
#define SS 512
#define HH 768
#define HDD 32
#define NN (BB*SS)      // 8192 tokens
#define NT (LL*NN)      // 106496 GEMM rows

typedef __bf16 bf16x4 __attribute__((ext_vector_type(4)));
typedef __bf16 bf16x8 __attribute__((ext_vector_type(8)));
typedef float  f32x4  __attribute__((ext_vector_type(4)));

__device__ __forceinline__ float sigmoid_f(float x) {
    return 1.f / (1.f + __expf(-x));
}
// exact rational tanh: (1-e^-2|x|)/(1+e^-2|x|), sign-restored. No overflow.
__device__ __forceinline__ float tanh_fast(float x) {
    float ax = fabsf(x);
    float e  = __expf(-2.f * ax);
    float t  = (1.f - e) / (1.f + e);
    return copysignf(t, x);
}

// ---------------------------------------------------------------------------
// K0: pre-convert W = [Wi_f | Wi_b] (fp32 [768,96]x2) into Bt[col][k] bf16
// (192 x 768, transposed so MFMA B-frag reads are contiguous in k).
// ---------------------------------------------------------------------------
__global__ __launch_bounds__(256) void k_prep(
    const float* __restrict__ Wf, const float* __restrict__ Wb,
    __bf16* __restrict__ Bt)
{
    int idx = blockIdx.x * 256 + threadIdx.x;     // 192*768 total
    if (idx >= 192 * 768) return;
    int col = idx / 768, k = idx - col * 768;
    float v = (col < 96) ? Wf[(size_t)k * 96 + col]
                         : Wb[(size_t)k * 96 + col - 96];
    Bt[idx] = (__bf16)v;
}

// ---------------------------------------------------------------------------
// K1: input projection GEMM via bf16 MFMA (16x16x32).
// A = hidden_states as [NT,768] fp32 (converted to bf16 on the fly).
// Block tile 128x192 (all N), BK=32, 4 waves in 2x2 (wm x wn) layout.
// Wave tile 64x96: M_rep=4, N_rep=6, acc = 24 f32x4 frags.
// LDS strides padded to 40 bf16 (80 B): 16B-aligned b128 frag reads, ~2-way
// bank aliasing only (free per m136).
// Correctness note: contiguous k-chunk frag loads are valid for ANY internal
// HW k-order because A and B use the identical (group,slot)->k mapping.
// ---------------------------------------------------------------------------
#define BMp 128
#define BKp 32
__global__ __launch_bounds__(256) void k_projm(
    const float* __restrict__ A, const __bf16* __restrict__ Bt,
    const float* __restrict__ bfv, const float* __restrict__ bbv,
    float* __restrict__ xpf, float* __restrict__ xpb)
{
    __shared__ __bf16 Al[BMp * 40];     // [row][k] stride 40
    __shared__ __bf16 Bl[192 * 40];     // [col][k] stride 40

    const int t    = threadIdx.x;
    const int r0   = blockIdx.x * BMp;
    const int wave = t >> 6, lane = t & 63;
    const int wm   = wave >> 1;          // 0..1 -> 64-row half
    const int wn   = wave & 1;           // 0..1 -> 96-col half (fw / bw)
    const int lr   = lane & 15;
    const int lg   = lane >> 4;

    f32x4 acc[4][6];
    #pragma unroll
    for (int m = 0; m < 4; ++m)
        #pragma unroll
        for (int n = 0; n < 6; ++n)
            acc[m][n] = (f32x4){0.f, 0.f, 0.f, 0.f};

    for (int k0 = 0; k0 < HH; k0 += BKp) {
        // stage A: 128 rows x 32 k fp32 -> bf16. 1024 float4s, 4/thread.
        #pragma unroll
        for (int i = 0; i < 4; ++i) {
            int f = i * 256 + t;
            int row = f >> 3, c4 = f & 7;
            float4 av = *(const float4*)(A + (size_t)(r0 + row) * HH + k0 + c4 * 4);
            bf16x4 bv;
            bv[0] = (__bf16)av.x; bv[1] = (__bf16)av.y;
            bv[2] = (__bf16)av.z; bv[3] = (__bf16)av.w;
            *(bf16x4*)(&Al[row * 40 + c4 * 4]) = bv;
        }
        // stage B: 192 cols x 32 k bf16, 768 16B-chunks, 3/thread.
        #pragma unroll
        for (int i = 0; i < 3; ++i) {
            int f = i * 256 + t;
            int col = f >> 2, c8 = f & 3;
            bf16x8 bv = *(const bf16x8*)(Bt + (size_t)col * HH + k0 + c8 * 8);
            *(bf16x8*)(&Bl[col * 40 + c8 * 8]) = bv;
        }
        __syncthreads();

        bf16x8 af[4], bfr[6];
        #pragma unroll
        for (int m = 0; m < 4; ++m)
            af[m] = *(const bf16x8*)(&Al[(wm * 64 + m * 16 + lr) * 40 + lg * 8]);
        #pragma unroll
        for (int n = 0; n < 6; ++n)
            bfr[n] = *(const bf16x8*)(&Bl[(wn * 96 + n * 16 + lr) * 40 + lg * 8]);
        #pragma unroll
        for (int m = 0; m < 4; ++m)
            #pragma unroll
            for (int n = 0; n < 6; ++n)
                acc[m][n] = __builtin_amdgcn_mfma_f32_16x16x32_bf16(
                    af[m], bfr[n], acc[m][n], 0, 0, 0);
        __syncthreads();
    }

    // epilogue: wn selects fw/bw buffer wholesale (wave-uniform).
    const float* bsrc = wn ? bbv : bfv;   // row 0 = input bias
    float*       dst  = wn ? xpb : xpf;
    float bias[6];
    #pragma unroll
    for (int n = 0; n < 6; ++n) bias[n] = bsrc[n * 16 + lr];
    #pragma unroll
    for (int m = 0; m < 4; ++m) {
        #pragma unroll
        for (int j = 0; j < 4; ++j) {
            size_t row = (size_t)(r0 + wm * 64 + m * 16 + lg * 4 + j);
            #pragma unroll
            for (int n = 0; n < 6; ++n)
                dst[row * 96 + n * 16 + lr] = acc[m][n][j] + bias[n];
        }
    }
}

// ---------------------------------------------------------------------------
// K2: GRU scans, 32 lanes per sequence (one hidden unit per lane).
// Uh columns live in 96 VGPRs; h broadcast via __shfl(width=32).
// blockIdx.y = direction. Writes lcf / lcb separately.
// ---------------------------------------------------------------------------
__global__ __launch_bounds__(256) void k_gru32(
    const float* __restrict__ xpf, const float* __restrict__ xpb,
    const float* __restrict__ Uf, const float* __restrict__ Ub,
    const float* __restrict__ bf_, const float* __restrict__ bb_,
    float* __restrict__ lcf, float* __restrict__ lcb)
{
    const int rev = blockIdx.y;
    const float* xp = rev ? xpb : xpf;
    const float* U  = rev ? Ub  : Uf;
    const float* bi = rev ? bb_ : bf_;
    float*      lco = rev ? lcb : lcf;

    const int t   = threadIdx.x;
    const int j   = t & 31;
    const int seq = blockIdx.x * 8 + (t >> 5);

    float Uz[32], Ur[32], Uh_[32];
    #pragma unroll
    for (int m = 0; m < 32; ++m) {
        Uz[m]  = U[m * 96 + j];
        Ur[m]  = U[m * 96 + 32 + j];
        Uh_[m] = U[m * 96 + 64 + j];
    }
    const float bz = bi[96 + j], br = bi[128 + j], bh = bi[160 + j];

    float h = 0.f;
    #pragma unroll 1
    for (int s = 0; s < LL; ++s) {
        const int tt = rev ? (LL - 1 - s) : s;
        const float* xr_ = xp + ((size_t)tt * NN + seq) * 96;
        float xz = xr_[j], xr = xr_[32 + j], xh = xr_[64 + j];
        float rz = bz, rr = br, rh = bh;
        #pragma unroll
        for (int m = 0; m < 32; ++m) {
            float hm = __shfl(h, m, 32);
            rz = fmaf(hm, Uz[m], rz);
            rr = fmaf(hm, Ur[m], rr);
            rh = fmaf(hm, Uh_[m], rh);
        }
        float z  = sigmoid_f(xz + rz);
        float r  = sigmoid_f(xr + rr);
        float hh = tanh_fast(xh + r * rh);
        h = z * h + (1.f - z) * hh;
    }
    lco[(size_t)seq * 32 + j] = h;
}

// ---------------------------------------------------------------------------
// K3: corrected = hs_last + tanh((lcf+lcb) @ W_lin + b_lin); partial sums
// over 32-token chunks. Grid (16,16); thread owns cols {t, t+256, t+512}.
// ---------------------------------------------------------------------------
__global__ __launch_bounds__(256) void k_corr(
    const float* __restrict__ hs_last, const float* __restrict__ lcf,
    const float* __restrict__ lcb, const float* __restrict__ Wlin,
    const float* __restrict__ blin, float* __restrict__ partial)
{
    __shared__ float lcl[32 * 32];
    const int t  = threadIdx.x;
    const int b  = blockIdx.x;   // 0..15
    const int sc = blockIdx.y;   // 0..15
    const int s0 = sc * 32;

    for (int i = t; i < 32 * 32; i += 256) {
        size_t idx = ((size_t)b * SS + s0) * 32 + i;
        lcl[i] = lcf[idx] + lcb[idx];
    }
    __syncthreads();

    float Wc[32][3];
    #pragma unroll
    for (int jj = 0; jj < 32; ++jj) {
        Wc[jj][0] = Wlin[(size_t)jj * HH + t];
        Wc[jj][1] = Wlin[(size_t)jj * HH + t + 256];
        Wc[jj][2] = Wlin[(size_t)jj * HH + t + 512];
    }
    const float bl0 = blin[t], bl1 = blin[t + 256], bl2 = blin[t + 512];

    float acc0 = 0.f, acc1 = 0.f, acc2 = 0.f;
    #pragma unroll 1
    for (int s = 0; s < 32; ++s) {
        float v0 = bl0, v1 = bl1, v2 = bl2;
        #pragma unroll
        for (int jj = 0; jj < 32; ++jj) {
            const float l = lcl[s * 32 + jj];
            v0 = fmaf(l, Wc[jj][0], v0);
            v1 = fmaf(l, Wc[jj][1], v1);
            v2 = fmaf(l, Wc[jj][2], v2);
        }
        const float* hp = hs_last + ((size_t)b * SS + s0 + s) * HH;
        acc0 += hp[t]       + tanh_fast(v0);
        acc1 += hp[t + 256] + tanh_fast(v1);
        acc2 += hp[t + 512] + tanh_fast(v2);
    }
    float* pp = partial + ((size_t)b * 16 + sc) * HH;
    pp[t] = acc0; pp[t + 256] = acc1; pp[t + 512] = acc2;
}

// ---------------------------------------------------------------------------
// K4: final pooling + classifier + softmax (tiny). One block.
// ---------------------------------------------------------------------------
__global__ __launch_bounds__(256) void k_final(
    const float* __restrict__ partial, const float* __restrict__ Wcls,
    const float* __restrict__ bcls, float* __restrict__ out)
{
    __shared__ float pooled[16 * HH];
    __shared__ float logits[48];
    const int t = threadIdx.x;
    for (int i = t; i < 16 * HH; i += 256) {
        int b = i / HH, h = i - b * HH;
        float s = 0.f;
        #pragma unroll
        for (int c = 0; c < 16; ++c) s += partial[((size_t)b * 16 + c) * HH + h];
        pooled[i] = s * (1.f / (float)SS);
    }
    __syncthreads();
    if (t < 48) {
        int b = t / 3, c = t - (t / 3) * 3;
        float s = bcls[c];
        for (int h = 0; h < HH; ++h)
            s = fmaf(pooled[b * HH + h], Wcls[h * 3 + c], s);
        logits[t] = s;
    }
    __syncthreads();
    if (t < 16) {
        float l0 = logits[t * 3], l1 = logits[t * 3 + 1], l2 = logits[t * 3 + 2];
        float m = fmaxf(l0, fmaxf(l1, l2));
        float e0 = __expf(l0 - m), e1 = __expf(l1 - m), e2 = __expf(l2 - m);
        float inv = 1.f / (e0 + e1 + e2);
        out[t * 3 + 0] = e0 * inv;
        out[t * 3 + 1] = e1 * inv;
        out[t * 3 + 2] = e2 * inv;
    }
}

// ---------------------------------------------------------------------------
extern "C" void kernel_launch(void* const* d_in, const int* in_sizes, int n_in,
                              void* d_out, int out_size, void* d_ws, size_t ws_size,
                              hipStream_t stream)
{
    const float* hs    = (const float*)d_in[0];
    const float* Wi_f  = (const float*)d_in[1];
    const float* Uh_f  = (const float*)d_in[2];
    const float* b_f   = (const float*)d_in[3];
    const float* Wi_b  = (const float*)d_in[4];
    const float* Uh_b  = (const float*)d_in[5];
    const float* b_b   = (const float*)d_in[6];
    const float* W_lin = (const float*)d_in[7];
    const float* b_lin = (const float*)d_in[8];
    const float* W_cls = (const float*)d_in[9];
    const float* b_cls = (const float*)d_in[10];

    float* ws      = (float*)d_ws;
    float* xpf     = ws;                                // NT*96
    float* xpb     = xpf + (size_t)NT * 96;             // NT*96
    float* lcf     = xpb + (size_t)NT * 96;             // NN*32
    float* lcb     = lcf + (size_t)NN * 32;             // NN*32
    float* partial = lcb + (size_t)NN * 32;             // 16*16*768 (786 KB)
    // Bt (192*768 bf16 = 288 KB) aliases `partial`: dead by the time k_corr
    // writes partial (stream-serial: k_prep/k_projm finish first).
    __bf16* Bt     = (__bf16*)partial;
    float* out     = (float*)d_out;

    k_prep<<<(192 * 768 + 255) / 256, 256, 0, stream>>>(Wi_f, Wi_b, Bt);
    k_projm<<<NT / BMp, 256, 0, stream>>>(hs, Bt, b_f, b_b, xpf, xpb);
    k_gru32<<<dim3(NN * 32 / 256, 2), 256, 0, stream>>>(xpf, xpb, Uh_f, Uh_b,
                                                        b_f, b_b, lcf, lcb);
    k_corr<<<dim3(16, 16), 256, 0, stream>>>(hs + (size_t)12 * NN * HH, lcf, lcb,
                                             W_lin, b_lin, partial);
    k_final<<<1, 256, 0, stream>>>(partial, W_cls, b_cls, out);
}

// Round 6
// 589.733 us; speedup vs baseline: 1.5946x; 1.0018x over previous
//
#include <hip/hip_runtime.h>
#include <hip/hip_bf16.h>
#include <math.h>

// Problem constants
#define LL 13
#define BB 16
#define SS 512
#define HH 768
#define HDD 32
#define NN (BB*SS)      // 8192 tokens
#define NT (LL*NN)      // 106496 GEMM rows

typedef __bf16 bf16x4 __attribute__((ext_vector_type(4)));
typedef __bf16 bf16x8 __attribute__((ext_vector_type(8)));
typedef float  f32x4  __attribute__((ext_vector_type(4)));

__device__ __forceinline__ float sigmoid_f(float x) {
    return 1.f / (1.f + __expf(-x));
}
// exact rational tanh: (1-e^-2|x|)/(1+e^-2|x|), sign-restored. No overflow.
__device__ __forceinline__ float tanh_fast(float x) {
    float ax = fabsf(x);
    float e  = __expf(-2.f * ax);
    float t  = (1.f - e) / (1.f + e);
    return copysignf(t, x);
}

// ---------------------------------------------------------------------------
// K0: pre-convert W = [Wi_f | Wi_b] (fp32 [768,96]x2) into Bt[col][k] bf16
// (192 x 768, transposed so MFMA B-frag reads are contiguous in k).
// ---------------------------------------------------------------------------
__global__ __launch_bounds__(256) void k_prep(
    const float* __restrict__ Wf, const float* __restrict__ Wb,
    __bf16* __restrict__ Bt)
{
    int idx = blockIdx.x * 256 + threadIdx.x;     // 192*768 total
    if (idx >= 192 * 768) return;
    int col = idx / 768, k = idx - col * 768;
    float v = (col < 96) ? Wf[(size_t)k * 96 + col]
                         : Wb[(size_t)k * 96 + col - 96];
    Bt[idx] = (__bf16)v;
}

// ---------------------------------------------------------------------------
// K1: input projection GEMM via bf16 MFMA (16x16x32), 2-stage register
// software pipeline: global loads for K-tile k+1 are issued right after the
// first barrier of tile k and consumed (written to LDS) after the bottom
// barrier — HBM/L3 latency hides under ds_read + 24 MFMA (~600 cyc).
// Block tile 128x192 (all N), BK=32, 4 waves in 2x2 (wm x wn) layout.
// Wave tile 64x96: M_rep=4, N_rep=6, acc = 24 f32x4 frags.
// LDS stride 40 bf16 (80 B): 16B-aligned b128 reads, ~2-way bank alias (free).
// ---------------------------------------------------------------------------
#define BMp 128
#define BKp 32
__global__ __launch_bounds__(256) void k_projm(
    const float* __restrict__ A, const __bf16* __restrict__ Bt,
    const float* __restrict__ bfv, const float* __restrict__ bbv,
    float* __restrict__ xpf, float* __restrict__ xpb)
{
    __shared__ __bf16 Al[BMp * 40];     // [row][k] stride 40
    __shared__ __bf16 Bl[192 * 40];     // [col][k] stride 40

    const int t    = threadIdx.x;
    const int r0   = blockIdx.x * BMp;
    const int wave = t >> 6, lane = t & 63;
    const int wm   = wave >> 1;          // 0..1 -> 64-row half
    const int wn   = wave & 1;           // 0..1 -> 96-col half (fw / bw)
    const int lr   = lane & 15;
    const int lg   = lane >> 4;

    // staging coords: A = 8 thr/row x 4 row-groups; B = 4 chunks/col x 3 grp
    const int arow = t >> 3, ac4 = t & 7;
    const int bcol = t >> 2, bc8 = t & 3;
    const float*  Aip = A  + (size_t)(r0 + arow) * HH + ac4 * 4;
    const __bf16* Bip = Bt + (size_t)bcol * HH + bc8 * 8;

    f32x4 acc[4][6];
    #pragma unroll
    for (int m = 0; m < 4; ++m)
        #pragma unroll
        for (int n = 0; n < 6; ++n)
            acc[m][n] = (f32x4){0.f, 0.f, 0.f, 0.f};

    // prologue: issue k0=0 loads
    float4 avr[4];
    bf16x8 bvr[3];
    #pragma unroll
    for (int i = 0; i < 4; ++i)
        avr[i] = *(const float4*)(Aip + (size_t)i * 32 * HH);
    #pragma unroll
    for (int i = 0; i < 3; ++i)
        bvr[i] = *(const bf16x8*)(Bip + (size_t)i * 64 * HH);

    for (int k0 = 0; k0 < HH; k0 += BKp) {
        // write staged regs to LDS (A: fp32 -> bf16 here)
        #pragma unroll
        for (int i = 0; i < 4; ++i) {
            bf16x4 bv;
            bv[0] = (__bf16)avr[i].x; bv[1] = (__bf16)avr[i].y;
            bv[2] = (__bf16)avr[i].z; bv[3] = (__bf16)avr[i].w;
            *(bf16x4*)(&Al[(i * 32 + arow) * 40 + ac4 * 4]) = bv;
        }
        #pragma unroll
        for (int i = 0; i < 3; ++i)
            *(bf16x8*)(&Bl[(i * 64 + bcol) * 40 + bc8 * 8]) = bvr[i];
        __syncthreads();

        // prefetch next K-tile while this one computes
        if (k0 + BKp < HH) {
            #pragma unroll
            for (int i = 0; i < 4; ++i)
                avr[i] = *(const float4*)(Aip + (k0 + BKp) + (size_t)i * 32 * HH);
            #pragma unroll
            for (int i = 0; i < 3; ++i)
                bvr[i] = *(const bf16x8*)(Bip + (k0 + BKp) + (size_t)i * 64 * HH);
        }

        bf16x8 af[4], bfr[6];
        #pragma unroll
        for (int m = 0; m < 4; ++m)
            af[m] = *(const bf16x8*)(&Al[(wm * 64 + m * 16 + lr) * 40 + lg * 8]);
        #pragma unroll
        for (int n = 0; n < 6; ++n)
            bfr[n] = *(const bf16x8*)(&Bl[(wn * 96 + n * 16 + lr) * 40 + lg * 8]);
        #pragma unroll
        for (int m = 0; m < 4; ++m)
            #pragma unroll
            for (int n = 0; n < 6; ++n)
                acc[m][n] = __builtin_amdgcn_mfma_f32_16x16x32_bf16(
                    af[m], bfr[n], acc[m][n], 0, 0, 0);
        __syncthreads();
    }

    // epilogue: wn selects fw/bw buffer wholesale (wave-uniform).
    const float* bsrc = wn ? bbv : bfv;   // row 0 = input bias
    float*       dst  = wn ? xpb : xpf;
    float bias[6];
    #pragma unroll
    for (int n = 0; n < 6; ++n) bias[n] = bsrc[n * 16 + lr];
    #pragma unroll
    for (int m = 0; m < 4; ++m) {
        #pragma unroll
        for (int j = 0; j < 4; ++j) {
            size_t row = (size_t)(r0 + wm * 64 + m * 16 + lg * 4 + j);
            #pragma unroll
            for (int n = 0; n < 6; ++n)
                dst[row * 96 + n * 16 + lr] = acc[m][n][j] + bias[n];
        }
    }
}

// ---------------------------------------------------------------------------
// K2: GRU scans, 32 lanes per sequence (one hidden unit per lane).
// Uh columns live in 96 VGPRs; h broadcast via __shfl(width=32).
// Step s+1's x-projections are prefetched before step s's FMA chain so the
// L3/HBM latency hides under the 32-deep recurrence compute.
// blockIdx.y = direction. Writes lcf / lcb separately.
// ---------------------------------------------------------------------------
__global__ __launch_bounds__(256) void k_gru32(
    const float* __restrict__ xpf, const float* __restrict__ xpb,
    const float* __restrict__ Uf, const float* __restrict__ Ub,
    const float* __restrict__ bf_, const float* __restrict__ bb_,
    float* __restrict__ lcf, float* __restrict__ lcb)
{
    const int rev = blockIdx.y;
    const float* xp = rev ? xpb : xpf;
    const float* U  = rev ? Ub  : Uf;
    const float* bi = rev ? bb_ : bf_;
    float*      lco = rev ? lcb : lcf;

    const int t   = threadIdx.x;
    const int j   = t & 31;
    const int seq = blockIdx.x * 8 + (t >> 5);

    float Uz[32], Ur[32], Uh_[32];
    #pragma unroll
    for (int m = 0; m < 32; ++m) {
        Uz[m]  = U[m * 96 + j];
        Ur[m]  = U[m * 96 + 32 + j];
        Uh_[m] = U[m * 96 + 64 + j];
    }
    const float bz = bi[96 + j], br = bi[128 + j], bh = bi[160 + j];

    float h = 0.f;
    const int tt0 = rev ? (LL - 1) : 0;
    const float* xq = xp + ((size_t)tt0 * NN + seq) * 96;
    float xz = xq[j], xr = xq[32 + j], xh = xq[64 + j];

    #pragma unroll 1
    for (int s = 0; s < LL; ++s) {
        // prefetch next step's x while the recurrence chain runs
        float nz = 0.f, nr = 0.f, nh = 0.f;
        if (s + 1 < LL) {
            const int tn = rev ? (LL - 2 - s) : (s + 1);
            const float* xn = xp + ((size_t)tn * NN + seq) * 96;
            nz = xn[j]; nr = xn[32 + j]; nh = xn[64 + j];
        }
        float rz = bz, rr = br, rh = bh;
        #pragma unroll
        for (int m = 0; m < 32; ++m) {
            float hm = __shfl(h, m, 32);
            rz = fmaf(hm, Uz[m], rz);
            rr = fmaf(hm, Ur[m], rr);
            rh = fmaf(hm, Uh_[m], rh);
        }
        float z   = sigmoid_f(xz + rz);
        float r   = sigmoid_f(xr + rr);
        float hhv = tanh_fast(xh + r * rh);
        h = z * h + (1.f - z) * hhv;
        xz = nz; xr = nr; xh = nh;
    }
    lco[(size_t)seq * 32 + j] = h;
}

// ---------------------------------------------------------------------------
// K3: corrected = hs_last + tanh((lcf+lcb) @ W_lin + b_lin); partial sums
// over 32-token chunks. Grid (16,16); thread owns cols {t, t+256, t+512}.
// ---------------------------------------------------------------------------
__global__ __launch_bounds__(256) void k_corr(
    const float* __restrict__ hs_last, const float* __restrict__ lcf,
    const float* __restrict__ lcb, const float* __restrict__ Wlin,
    const float* __restrict__ blin, float* __restrict__ partial)
{
    __shared__ float lcl[32 * 32];
    const int t  = threadIdx.x;
    const int b  = blockIdx.x;   // 0..15
    const int sc = blockIdx.y;   // 0..15
    const int s0 = sc * 32;

    for (int i = t; i < 32 * 32; i += 256) {
        size_t idx = ((size_t)b * SS + s0) * 32 + i;
        lcl[i] = lcf[idx] + lcb[idx];
    }
    __syncthreads();

    float Wc[32][3];
    #pragma unroll
    for (int jj = 0; jj < 32; ++jj) {
        Wc[jj][0] = Wlin[(size_t)jj * HH + t];
        Wc[jj][1] = Wlin[(size_t)jj * HH + t + 256];
        Wc[jj][2] = Wlin[(size_t)jj * HH + t + 512];
    }
    const float bl0 = blin[t], bl1 = blin[t + 256], bl2 = blin[t + 512];

    float acc0 = 0.f, acc1 = 0.f, acc2 = 0.f;
    #pragma unroll 1
    for (int s = 0; s < 32; ++s) {
        float v0 = bl0, v1 = bl1, v2 = bl2;
        #pragma unroll
        for (int jj = 0; jj < 32; ++jj) {
            const float l = lcl[s * 32 + jj];
            v0 = fmaf(l, Wc[jj][0], v0);
            v1 = fmaf(l, Wc[jj][1], v1);
            v2 = fmaf(l, Wc[jj][2], v2);
        }
        const float* hp = hs_last + ((size_t)b * SS + s0 + s) * HH;
        acc0 += hp[t]       + tanh_fast(v0);
        acc1 += hp[t + 256] + tanh_fast(v1);
        acc2 += hp[t + 512] + tanh_fast(v2);
    }
    float* pp = partial + ((size_t)b * 16 + sc) * HH;
    pp[t] = acc0; pp[t + 256] = acc1; pp[t + 512] = acc2;
}

// ---------------------------------------------------------------------------
// K4: final pooling + classifier + softmax (tiny). One block.
// ---------------------------------------------------------------------------
__global__ __launch_bounds__(256) void k_final(
    const float* __restrict__ partial, const float* __restrict__ Wcls,
    const float* __restrict__ bcls, float* __restrict__ out)
{
    __shared__ float pooled[16 * HH];
    __shared__ float logits[48];
    const int t = threadIdx.x;
    for (int i = t; i < 16 * HH; i += 256) {
        int b = i / HH, h = i - b * HH;
        float s = 0.f;
        #pragma unroll
        for (int c = 0; c < 16; ++c) s += partial[((size_t)b * 16 + c) * HH + h];
        pooled[i] = s * (1.f / (float)SS);
    }
    __syncthreads();
    if (t < 48) {
        int b = t / 3, c = t - (t / 3) * 3;
        float s = bcls[c];
        for (int h = 0; h < HH; ++h)
            s = fmaf(pooled[b * HH + h], Wcls[h * 3 + c], s);
        logits[t] = s;
    }
    __syncthreads();
    if (t < 16) {
        float l0 = logits[t * 3], l1 = logits[t * 3 + 1], l2 = logits[t * 3 + 2];
        float m = fmaxf(l0, fmaxf(l1, l2));
        float e0 = __expf(l0 - m), e1 = __expf(l1 - m), e2 = __expf(l2 - m);
        float inv = 1.f / (e0 + e1 + e2);
        out[t * 3 + 0] = e0 * inv;
        out[t * 3 + 1] = e1 * inv;
        out[t * 3 + 2] = e2 * inv;
    }
}

// ---------------------------------------------------------------------------
extern "C" void kernel_launch(void* const* d_in, const int* in_sizes, int n_in,
                              void* d_out, int out_size, void* d_ws, size_t ws_size,
                              hipStream_t stream)
{
    const float* hs    = (const float*)d_in[0];
    const float* Wi_f  = (const float*)d_in[1];
    const float* Uh_f  = (const float*)d_in[2];
    const float* b_f   = (const float*)d_in[3];
    const float* Wi_b  = (const float*)d_in[4];
    const float* Uh_b  = (const float*)d_in[5];
    const float* b_b   = (const float*)d_in[6];
    const float* W_lin = (const float*)d_in[7];
    const float* b_lin = (const float*)d_in[8];
    const float* W_cls = (const float*)d_in[9];
    const float* b_cls = (const float*)d_in[10];

    float* ws      = (float*)d_ws;
    float* xpf     = ws;                                // NT*96
    float* xpb     = xpf + (size_t)NT * 96;             // NT*96
    float* lcf     = xpb + (size_t)NT * 96;             // NN*32
    float* lcb     = lcf + (size_t)NN * 32;             // NN*32
    float* partial = lcb + (size_t)NN * 32;             // 16*16*768 (786 KB)
    // Bt (192*768 bf16 = 288 KB) aliases `partial`: dead by the time k_corr
    // writes partial (stream-serial: k_prep/k_projm finish first).
    __bf16* Bt     = (__bf16*)partial;
    float* out     = (float*)d_out;

    k_prep<<<(192 * 768 + 255) / 256, 256, 0, stream>>>(Wi_f, Wi_b, Bt);
    k_projm<<<NT / BMp, 256, 0, stream>>>(hs, Bt, b_f, b_b, xpf, xpb);
    k_gru32<<<dim3(NN * 32 / 256, 2), 256, 0, stream>>>(xpf, xpb, Uh_f, Uh_b,
                                                        b_f, b_b, lcf, lcb);
    k_corr<<<dim3(16, 16), 256, 0, stream>>>(hs + (size_t)12 * NN * HH, lcf, lcb,
                                             W_lin, b_lin, partial);
    k_final<<<1, 256, 0, stream>>>(partial, W_cls, b_cls, out);
}

// Round 11
// 540.576 us; speedup vs baseline: 1.7396x; 1.0909x over previous
//
#include <hip/hip_runtime.h>
#include <hip/hip_bf16.h>
#include <math.h>

// Problem constants
#define LL 13
#define BB 16
#define SS 512
#define HH 768
#define HDD 32
#define NN (BB*SS)      // 8192 tokens
#define NT (LL*NN)      // 106496 GEMM rows

typedef __bf16 bf16x4 __attribute__((ext_vector_type(4)));
typedef __bf16 bf16x8 __attribute__((ext_vector_type(8)));
typedef float  f32x4  __attribute__((ext_vector_type(4)));

__device__ __forceinline__ float sigmoid_f(float x) {
    return 1.f / (1.f + __expf(-x));
}
// exact rational tanh: (1-e^-2|x|)/(1+e^-2|x|), sign-restored. No overflow.
__device__ __forceinline__ float tanh_fast(float x) {
    float ax = fabsf(x);
    float e  = __expf(-2.f * ax);
    float t  = (1.f - e) / (1.f + e);
    return copysignf(t, x);
}

// ---------------------------------------------------------------------------
// K0: pre-convert W = [Wi_f | Wi_b] (fp32 [768,96]x2) into Bt[col][k] bf16
// (192 x 768, transposed so MFMA B-frag reads are contiguous in k).
// ---------------------------------------------------------------------------
__global__ __launch_bounds__(256) void k_prep(
    const float* __restrict__ Wf, const float* __restrict__ Wb,
    __bf16* __restrict__ Bt)
{
    int idx = blockIdx.x * 256 + threadIdx.x;     // 192*768 total
    if (idx >= 192 * 768) return;
    int col = idx / 768, k = idx - col * 768;
    float v = (col < 96) ? Wf[(size_t)k * 96 + col]
                         : Wb[(size_t)k * 96 + col - 96];
    Bt[idx] = (__bf16)v;
}

// ---------------------------------------------------------------------------
// K1: input projection GEMM via bf16 MFMA (16x16x32), 2-stage register
// software pipeline (R6: neutral, kept — costs nothing). Output bf16:
// halves xp write traffic (82 -> 41 MB) and the GRU's read traffic.
// Block tile 128x192 (all N), BK=32, 4 waves 2x2. Wave tile 64x96.
// LDS stride 40 bf16: 16B-aligned b128 reads, 2-way bank alias (free, m136).
// ---------------------------------------------------------------------------
#define BMp 128
#define BKp 32
__global__ __launch_bounds__(256) void k_projm(
    const float* __restrict__ A, const __bf16* __restrict__ Bt,
    const float* __restrict__ bfv, const float* __restrict__ bbv,
    __bf16* __restrict__ xpf, __bf16* __restrict__ xpb)
{
    __shared__ __bf16 Al[BMp * 40];     // [row][k] stride 40
    __shared__ __bf16 Bl[192 * 40];     // [col][k] stride 40

    const int t    = threadIdx.x;
    const int r0   = blockIdx.x * BMp;
    const int wave = t >> 6, lane = t & 63;
    const int wm   = wave >> 1;          // 0..1 -> 64-row half
    const int wn   = wave & 1;           // 0..1 -> 96-col half (fw / bw)
    const int lr   = lane & 15;
    const int lg   = lane >> 4;

    // staging coords: A = 8 thr/row x 4 row-groups; B = 4 chunks/col x 3 grp
    const int arow = t >> 3, ac4 = t & 7;
    const int bcol = t >> 2, bc8 = t & 3;
    const float*  Aip = A  + (size_t)(r0 + arow) * HH + ac4 * 4;
    const __bf16* Bip = Bt + (size_t)bcol * HH + bc8 * 8;

    f32x4 acc[4][6];
    #pragma unroll
    for (int m = 0; m < 4; ++m)
        #pragma unroll
        for (int n = 0; n < 6; ++n)
            acc[m][n] = (f32x4){0.f, 0.f, 0.f, 0.f};

    // prologue: issue k0=0 loads
    float4 avr[4];
    bf16x8 bvr[3];
    #pragma unroll
    for (int i = 0; i < 4; ++i)
        avr[i] = *(const float4*)(Aip + (size_t)i * 32 * HH);
    #pragma unroll
    for (int i = 0; i < 3; ++i)
        bvr[i] = *(const bf16x8*)(Bip + (size_t)i * 64 * HH);

    for (int k0 = 0; k0 < HH; k0 += BKp) {
        // write staged regs to LDS (A: fp32 -> bf16 here)
        #pragma unroll
        for (int i = 0; i < 4; ++i) {
            bf16x4 bv;
            bv[0] = (__bf16)avr[i].x; bv[1] = (__bf16)avr[i].y;
            bv[2] = (__bf16)avr[i].z; bv[3] = (__bf16)avr[i].w;
            *(bf16x4*)(&Al[(i * 32 + arow) * 40 + ac4 * 4]) = bv;
        }
        #pragma unroll
        for (int i = 0; i < 3; ++i)
            *(bf16x8*)(&Bl[(i * 64 + bcol) * 40 + bc8 * 8]) = bvr[i];
        __syncthreads();

        // prefetch next K-tile while this one computes
        if (k0 + BKp < HH) {
            #pragma unroll
            for (int i = 0; i < 4; ++i)
                avr[i] = *(const float4*)(Aip + (k0 + BKp) + (size_t)i * 32 * HH);
            #pragma unroll
            for (int i = 0; i < 3; ++i)
                bvr[i] = *(const bf16x8*)(Bip + (k0 + BKp) + (size_t)i * 64 * HH);
        }

        bf16x8 af[4], bfr[6];
        #pragma unroll
        for (int m = 0; m < 4; ++m)
            af[m] = *(const bf16x8*)(&Al[(wm * 64 + m * 16 + lr) * 40 + lg * 8]);
        #pragma unroll
        for (int n = 0; n < 6; ++n)
            bfr[n] = *(const bf16x8*)(&Bl[(wn * 96 + n * 16 + lr) * 40 + lg * 8]);
        #pragma unroll
        for (int m = 0; m < 4; ++m)
            #pragma unroll
            for (int n = 0; n < 6; ++n)
                acc[m][n] = __builtin_amdgcn_mfma_f32_16x16x32_bf16(
                    af[m], bfr[n], acc[m][n], 0, 0, 0);
        __syncthreads();
    }

    // epilogue: wn selects fw/bw buffer wholesale (wave-uniform). bf16 store.
    const float* bsrc = wn ? bbv : bfv;   // row 0 = input bias
    __bf16*      dst  = wn ? xpb : xpf;
    float bias[6];
    #pragma unroll
    for (int n = 0; n < 6; ++n) bias[n] = bsrc[n * 16 + lr];
    #pragma unroll
    for (int m = 0; m < 4; ++m) {
        #pragma unroll
        for (int j = 0; j < 4; ++j) {
            size_t row = (size_t)(r0 + wm * 64 + m * 16 + lg * 4 + j);
            #pragma unroll
            for (int n = 0; n < 6; ++n)
                dst[row * 96 + n * 16 + lr] = (__bf16)(acc[m][n][j] + bias[n]);
        }
    }
}

// ---------------------------------------------------------------------------
// K2: GRU scans, 32 lanes per sequence (one hidden unit per lane).
// Uh columns live in 96 VGPRs; h broadcast via __shfl(width=32).
// xp bf16 (halved read traffic); recurrence stays fp32.
// blockIdx.y = direction. Writes lcf / lcb separately.
// ---------------------------------------------------------------------------
__global__ __launch_bounds__(256) void k_gru32(
    const __bf16* __restrict__ xpf, const __bf16* __restrict__ xpb,
    const float* __restrict__ Uf, const float* __restrict__ Ub,
    const float* __restrict__ bf_, const float* __restrict__ bb_,
    float* __restrict__ lcf, float* __restrict__ lcb)
{
    const int rev = blockIdx.y;
    const __bf16* xp = rev ? xpb : xpf;
    const float*  U  = rev ? Ub  : Uf;
    const float*  bi = rev ? bb_ : bf_;
    float*       lco = rev ? lcb : lcf;

    const int t   = threadIdx.x;
    const int j   = t & 31;
    const int seq = blockIdx.x * 8 + (t >> 5);

    float Uz[32], Ur[32], Uh_[32];
    #pragma unroll
    for (int m = 0; m < 32; ++m) {
        Uz[m]  = U[m * 96 + j];
        Ur[m]  = U[m * 96 + 32 + j];
        Uh_[m] = U[m * 96 + 64 + j];
    }
    const float bz = bi[96 + j], br = bi[128 + j], bh = bi[160 + j];

    float h = 0.f;
    const int tt0 = rev ? (LL - 1) : 0;
    const __bf16* xq = xp + ((size_t)tt0 * NN + seq) * 96;
    float xz = (float)xq[j], xr = (float)xq[32 + j], xh = (float)xq[64 + j];

    #pragma unroll 1
    for (int s = 0; s < LL; ++s) {
        // prefetch next step's x while the recurrence chain runs
        float nz = 0.f, nr = 0.f, nh = 0.f;
        if (s + 1 < LL) {
            const int tn = rev ? (LL - 2 - s) : (s + 1);
            const __bf16* xn = xp + ((size_t)tn * NN + seq) * 96;
            nz = (float)xn[j]; nr = (float)xn[32 + j]; nh = (float)xn[64 + j];
        }
        float rz = bz, rr = br, rh = bh;
        #pragma unroll
        for (int m = 0; m < 32; ++m) {
            float hm = __shfl(h, m, 32);
            rz = fmaf(hm, Uz[m], rz);
            rr = fmaf(hm, Ur[m], rr);
            rh = fmaf(hm, Uh_[m], rh);
        }
        float z   = sigmoid_f(xz + rz);
        float r   = sigmoid_f(xr + rr);
        float hhv = tanh_fast(xh + r * rh);
        h = z * h + (1.f - z) * hhv;
        xz = nz; xr = nr; xh = nh;
    }
    lco[(size_t)seq * 32 + j] = h;
}

// ---------------------------------------------------------------------------
// K3: corrected = hs_last + tanh((lcf+lcb) @ W_lin + b_lin); partial sums
// over 32-token chunks. Grid (16,16); thread owns cols {t, t+256, t+512}.
// ---------------------------------------------------------------------------
__global__ __launch_bounds__(256) void k_corr(
    const float* __restrict__ hs_last, const float* __restrict__ lcf,
    const float* __restrict__ lcb, const float* __restrict__ Wlin,
    const float* __restrict__ blin, float* __restrict__ partial)
{
    __shared__ float lcl[32 * 32];
    const int t  = threadIdx.x;
    const int b  = blockIdx.x;   // 0..15
    const int sc = blockIdx.y;   // 0..15
    const int s0 = sc * 32;

    for (int i = t; i < 32 * 32; i += 256) {
        size_t idx = ((size_t)b * SS + s0) * 32 + i;
        lcl[i] = lcf[idx] + lcb[idx];
    }
    __syncthreads();

    float Wc[32][3];
    #pragma unroll
    for (int jj = 0; jj < 32; ++jj) {
        Wc[jj][0] = Wlin[(size_t)jj * HH + t];
        Wc[jj][1] = Wlin[(size_t)jj * HH + t + 256];
        Wc[jj][2] = Wlin[(size_t)jj * HH + t + 512];
    }
    const float bl0 = blin[t], bl1 = blin[t + 256], bl2 = blin[t + 512];

    float acc0 = 0.f, acc1 = 0.f, acc2 = 0.f;
    #pragma unroll 1
    for (int s = 0; s < 32; ++s) {
        float v0 = bl0, v1 = bl1, v2 = bl2;
        #pragma unroll
        for (int jj = 0; jj < 32; ++jj) {
            const float l = lcl[s * 32 + jj];
            v0 = fmaf(l, Wc[jj][0], v0);
            v1 = fmaf(l, Wc[jj][1], v1);
            v2 = fmaf(l, Wc[jj][2], v2);
        }
        const float* hp = hs_last + ((size_t)b * SS + s0 + s) * HH;
        acc0 += hp[t]       + tanh_fast(v0);
        acc1 += hp[t + 256] + tanh_fast(v1);
        acc2 += hp[t + 512] + tanh_fast(v2);
    }
    float* pp = partial + ((size_t)b * 16 + sc) * HH;
    pp[t] = acc0; pp[t + 256] = acc1; pp[t + 512] = acc2;
}

// ---------------------------------------------------------------------------
// K4: final pooling + classifier + softmax. One block PER BATCH ROW (16
// blocks) instead of a single serial block: removes the ~8 us 1-CU tail.
// Thread t owns h-positions {t, t+256, t+512}; logits via LDS tree-reduce.
// ---------------------------------------------------------------------------
__global__ __launch_bounds__(256) void k_final2(
    const float* __restrict__ partial, const float* __restrict__ Wcls,
    const float* __restrict__ bcls, float* __restrict__ out)
{
    const int b = blockIdx.x;    // 0..15
    const int t = threadIdx.x;

    float p0 = 0.f, p1 = 0.f, p2 = 0.f;
    #pragma unroll
    for (int c = 0; c < 16; ++c) {
        const float* pp = partial + ((size_t)b * 16 + c) * HH;
        p0 += pp[t]; p1 += pp[t + 256]; p2 += pp[t + 512];
    }
    const float inv = 1.f / (float)SS;
    p0 *= inv; p1 *= inv; p2 *= inv;

    __shared__ float red[3][256];
    #pragma unroll
    for (int c = 0; c < 3; ++c) {
        red[c][t] = p0 * Wcls[(size_t)t * 3 + c]
                  + p1 * Wcls[(size_t)(t + 256) * 3 + c]
                  + p2 * Wcls[(size_t)(t + 512) * 3 + c];
    }
    __syncthreads();
    for (int s = 128; s > 0; s >>= 1) {
        if (t < s) {
            red[0][t] += red[0][t + s];
            red[1][t] += red[1][t + s];
            red[2][t] += red[2][t + s];
        }
        __syncthreads();
    }
    if (t == 0) {
        float l0 = red[0][0] + bcls[0];
        float l1 = red[1][0] + bcls[1];
        float l2 = red[2][0] + bcls[2];
        float m  = fmaxf(l0, fmaxf(l1, l2));
        float e0 = __expf(l0 - m), e1 = __expf(l1 - m), e2 = __expf(l2 - m);
        float is = 1.f / (e0 + e1 + e2);
        out[b * 3 + 0] = e0 * is;
        out[b * 3 + 1] = e1 * is;
        out[b * 3 + 2] = e2 * is;
    }
}

// ---------------------------------------------------------------------------
extern "C" void kernel_launch(void* const* d_in, const int* in_sizes, int n_in,
                              void* d_out, int out_size, void* d_ws, size_t ws_size,
                              hipStream_t stream)
{
    const float* hs    = (const float*)d_in[0];
    const float* Wi_f  = (const float*)d_in[1];
    const float* Uh_f  = (const float*)d_in[2];
    const float* b_f   = (const float*)d_in[3];
    const float* Wi_b  = (const float*)d_in[4];
    const float* Uh_b  = (const float*)d_in[5];
    const float* b_b   = (const float*)d_in[6];
    const float* W_lin = (const float*)d_in[7];
    const float* b_lin = (const float*)d_in[8];
    const float* W_cls = (const float*)d_in[9];
    const float* b_cls = (const float*)d_in[10];

    // ws layout (all offsets 16B-aligned):
    //   xpf, xpb : bf16 NT*96 each (20.4 MB each)
    //   lcf, lcb : f32 NN*32 each (1 MB each)
    //   partial  : f32 16*16*768 (786 KB)
    //   Bt       : bf16 192*768 (288 KB)
    __bf16* xpf    = (__bf16*)d_ws;
    __bf16* xpb    = xpf + (size_t)NT * 96;
    float*  lcf    = (float*)(xpb + (size_t)NT * 96);
    float*  lcb    = lcf + (size_t)NN * 32;
    float*  partial= lcb + (size_t)NN * 32;
    __bf16* Bt     = (__bf16*)(partial + (size_t)16 * 16 * HH);
    float*  out    = (float*)d_out;

    k_prep<<<(192 * 768 + 255) / 256, 256, 0, stream>>>(Wi_f, Wi_b, Bt);
    k_projm<<<NT / BMp, 256, 0, stream>>>(hs, Bt, b_f, b_b, xpf, xpb);
    k_gru32<<<dim3(NN * 32 / 256, 2), 256, 0, stream>>>(xpf, xpb, Uh_f, Uh_b,
                                                        b_f, b_b, lcf, lcb);
    k_corr<<<dim3(16, 16), 256, 0, stream>>>(hs + (size_t)12 * NN * HH, lcf, lcb,
                                             W_lin, b_lin, partial);
    k_final2<<<16, 256, 0, stream>>>(partial, W_cls, b_cls, out);
}